// Round 1
// baseline (360.654 us; speedup 1.0000x reference)
//
#include <hip/hip_runtime.h>

#define N_NODES 50000
#define IN_DIM  128
#define OUT_DIM 256
#define N_EDGES 800000
#define SCAN_BLOCKS 49   // ceil(50000/1024)

// ---------------- CSR build ----------------

__global__ void k_hist(const int* __restrict__ ei, int* __restrict__ counts) {
    int e = blockIdx.x * 256 + threadIdx.x;
    if (e < N_EDGES) {
        int d = ei[2 * e + 1];
        atomicAdd(&counts[d], 1);
    }
}

__global__ void k_scan1(const int* __restrict__ counts, int* __restrict__ ptr,
                        int* __restrict__ bsum) {
    __shared__ int lds[1024];
    int i = blockIdx.x * 1024 + threadIdx.x;
    int v = (i < N_NODES) ? counts[i] : 0;
    lds[threadIdx.x] = v;
    __syncthreads();
    for (int off = 1; off < 1024; off <<= 1) {
        int t = (threadIdx.x >= off) ? lds[threadIdx.x - off] : 0;
        __syncthreads();
        lds[threadIdx.x] += t;
        __syncthreads();
    }
    if (i < N_NODES) ptr[i] = lds[threadIdx.x];       // inclusive within block
    if (threadIdx.x == 1023) bsum[blockIdx.x] = lds[1023];
}

__global__ void k_scan2(int* __restrict__ bsum) {
    if (blockIdx.x == 0 && threadIdx.x == 0) {
        int run = 0;
        for (int b = 0; b < SCAN_BLOCKS; ++b) {
            int t = bsum[b]; bsum[b] = run; run += t;
        }
    }
}

__global__ void k_finalize(int* __restrict__ ptr, const int* __restrict__ counts,
                           const int* __restrict__ bsum, float* __restrict__ dinv) {
    int i = blockIdx.x * 256 + threadIdx.x;
    if (i < N_NODES) {
        int incl = ptr[i] + bsum[i >> 10];
        ptr[i] = incl - counts[i];                    // exclusive start (cursor)
        dinv[i] = rsqrtf((float)(counts[i] + 1));     // +1 self-loop
    }
}

__global__ void k_scatter(const int* __restrict__ ei, int* __restrict__ ptr,
                          int* __restrict__ srcl) {
    int e = blockIdx.x * 256 + threadIdx.x;
    if (e < N_EDGES) {
        int s = ei[2 * e];
        int d = ei[2 * e + 1];
        int pos = atomicAdd(&ptr[d], 1);              // after: ptr[d] == end
        srcl[pos] = s;
    }
}

// ---------------- aggregation: y[i] = dinv[i]*(dinv[i]*x[i] + sum dinv[s]*x[s]) --------

__global__ __launch_bounds__(128) void k_aggregate(
        const float* __restrict__ x, const float* __restrict__ dinv,
        const int* __restrict__ ptr, const int* __restrict__ counts,
        const int* __restrict__ srcl, float* __restrict__ y) {
    __shared__ int   s_src[128];
    __shared__ float s_w[128];
    int i = blockIdx.x;
    int c = threadIdx.x;
    float di = dinv[i];
    int end = ptr[i];
    int start = end - counts[i];
    float sum = di * x[i * IN_DIM + c];               // self-loop term
    for (int e0 = start; e0 < end; e0 += 128) {
        int ne = end - e0; if (ne > 128) ne = 128;
        if (c < ne) {
            int s = srcl[e0 + c];
            s_src[c] = s;
            s_w[c] = dinv[s];
        }
        __syncthreads();
        for (int t = 0; t < ne; ++t) {
            sum += s_w[t] * x[s_src[t] * IN_DIM + c];
        }
        __syncthreads();
    }
    y[i * IN_DIM + c] = di * sum;
}

// ---------------- GEMM: out = relu(y @ W^T + b), fp32 ----------------
// 64(m) x 64(j) tile, K=128 in two 64-chunks. Swizzled LDS (no pad, b128-aligned,
// <=2-way banks). 256 threads, 4x4 acc each.

__device__ __forceinline__ int swz(int r, int c4) {
    return r * 64 + (((c4 + (r >> 2)) & 15) << 2);
}

__global__ __launch_bounds__(256) void k_gemm(
        const float* __restrict__ y, const float* __restrict__ W,
        const float* __restrict__ bias, float* __restrict__ out) {
    __shared__ float y_lds[64 * 64];
    __shared__ float w_lds[64 * 64];
    int tid = threadIdx.x;
    int i0 = blockIdx.x * 64;
    int jb = blockIdx.y * 64;
    int jg = tid & 15, mg = tid >> 4;
    int j0 = jg * 4, m0 = mg * 4;
    float acc[4][4] = {};

    for (int kc = 0; kc < IN_DIM; kc += 64) {
        __syncthreads();
        #pragma unroll
        for (int it = 0; it < 4; ++it) {
            int idx = it * 256 + tid;                 // 0..1023
            int r = idx >> 4;                         // 0..63
            int c4 = idx & 15;                        // float4 index along k
            int row = i0 + r; if (row > N_NODES - 1) row = N_NODES - 1;
            float4 v = *(const float4*)&y[row * IN_DIM + kc + c4 * 4];
            *(float4*)&y_lds[swz(r, c4)] = v;
            float4 wv = *(const float4*)&W[(jb + r) * IN_DIM + kc + c4 * 4];
            *(float4*)&w_lds[swz(r, c4)] = wv;
        }
        __syncthreads();
        #pragma unroll
        for (int k4 = 0; k4 < 16; ++k4) {
            float4 ym[4], wj[4];
            #pragma unroll
            for (int mm = 0; mm < 4; ++mm)
                ym[mm] = *(const float4*)&y_lds[swz(m0 + mm, k4)];
            #pragma unroll
            for (int jj = 0; jj < 4; ++jj)
                wj[jj] = *(const float4*)&w_lds[swz(j0 + jj, k4)];
            #pragma unroll
            for (int mm = 0; mm < 4; ++mm)
                #pragma unroll
                for (int jj = 0; jj < 4; ++jj)
                    acc[mm][jj] += ym[mm].x * wj[jj].x + ym[mm].y * wj[jj].y
                                 + ym[mm].z * wj[jj].z + ym[mm].w * wj[jj].w;
        }
    }

    float4 bv = *(const float4*)&bias[jb + j0];
    #pragma unroll
    for (int mm = 0; mm < 4; ++mm) {
        int row = i0 + m0 + mm;
        if (row < N_NODES) {
            float4 o;
            o.x = fmaxf(acc[mm][0] + bv.x, 0.f);
            o.y = fmaxf(acc[mm][1] + bv.y, 0.f);
            o.z = fmaxf(acc[mm][2] + bv.z, 0.f);
            o.w = fmaxf(acc[mm][3] + bv.w, 0.f);
            *(float4*)&out[row * OUT_DIM + jb + j0] = o;
        }
    }
}

// ---------------- launch ----------------

extern "C" void kernel_launch(void* const* d_in, const int* in_sizes, int n_in,
                              void* d_out, int out_size, void* d_ws, size_t ws_size,
                              hipStream_t stream) {
    const float* x  = (const float*)d_in[0];
    const int*   ei = (const int*)d_in[1];
    const float* W  = (const float*)d_in[2];
    const float* b  = (const float*)d_in[3];
    float* out = (float*)d_out;

    char* ws = (char*)d_ws;
    // workspace layout (bytes), ~29.4 MB total
    int*   counts = (int*)(ws + 0);          //  50000 ints
    int*   ptr    = (int*)(ws + 200704);     //  50000 ints
    int*   bsum   = (int*)(ws + 401408);     //  64 ints
    float* dinv   = (float*)(ws + 401664);   //  50000 floats
    int*   srcl   = (int*)(ws + 602368);     //  800000 ints
    float* y      = (float*)(ws + 3802368);  //  6400000 floats

    hipMemsetAsync(counts, 0, N_NODES * sizeof(int), stream);

    k_hist<<<(N_EDGES + 255) / 256, 256, 0, stream>>>(ei, counts);
    k_scan1<<<SCAN_BLOCKS, 1024, 0, stream>>>(counts, ptr, bsum);
    k_scan2<<<1, 64, 0, stream>>>(bsum);
    k_finalize<<<(N_NODES + 255) / 256, 256, 0, stream>>>(ptr, counts, bsum, dinv);
    k_scatter<<<(N_EDGES + 255) / 256, 256, 0, stream>>>(ei, ptr, srcl);
    k_aggregate<<<N_NODES, 128, 0, stream>>>(x, dinv, ptr, counts, srcl, y);

    dim3 g((N_NODES + 63) / 64, OUT_DIM / 64);
    k_gemm<<<g, 256, 0, stream>>>(y, W, b, out);
}

// Round 2
// 270.266 us; speedup vs baseline: 1.3344x; 1.3344x over previous
//
#include <hip/hip_runtime.h>

#define N_NODES 50000
#define IN_DIM  128
#define OUT_DIM 256
#define N_EDGES 800000
#define SCAN_BLOCKS 49   // ceil(50000/1024)

typedef short bf16x8 __attribute__((ext_vector_type(8)));   // 8 bf16 = 4 VGPRs
typedef float f32x4  __attribute__((ext_vector_type(4)));   // MFMA acc

// ---------------- CSR build ----------------

__global__ void k_hist(const int* __restrict__ ei, int* __restrict__ counts) {
    int e = blockIdx.x * 256 + threadIdx.x;
    if (e < N_EDGES) {
        int d = ei[2 * e + 1];
        atomicAdd(&counts[d], 1);
    }
}

__global__ void k_scan1(const int* __restrict__ counts, int* __restrict__ ptr,
                        int* __restrict__ bsum) {
    __shared__ int lds[1024];
    int i = blockIdx.x * 1024 + threadIdx.x;
    int v = (i < N_NODES) ? counts[i] : 0;
    lds[threadIdx.x] = v;
    __syncthreads();
    for (int off = 1; off < 1024; off <<= 1) {
        int t = (threadIdx.x >= off) ? lds[threadIdx.x - off] : 0;
        __syncthreads();
        lds[threadIdx.x] += t;
        __syncthreads();
    }
    if (i < N_NODES) ptr[i] = lds[threadIdx.x];       // inclusive within block
    if (threadIdx.x == 1023) bsum[blockIdx.x] = lds[1023];
}

__global__ void k_scan2(int* __restrict__ bsum) {
    if (blockIdx.x == 0 && threadIdx.x == 0) {
        int run = 0;
        for (int b = 0; b < SCAN_BLOCKS; ++b) {
            int t = bsum[b]; bsum[b] = run; run += t;
        }
    }
}

__global__ void k_finalize(int* __restrict__ ptr, const int* __restrict__ counts,
                           const int* __restrict__ bsum, float* __restrict__ dinv) {
    int i = blockIdx.x * 256 + threadIdx.x;
    if (i < N_NODES) {
        int incl = ptr[i] + bsum[i >> 10];
        ptr[i] = incl - counts[i];                    // exclusive start (cursor)
        dinv[i] = rsqrtf((float)(counts[i] + 1));     // +1 self-loop
    }
}

__global__ void k_scatter(const int* __restrict__ ei, int* __restrict__ ptr,
                          int* __restrict__ srcl) {
    int e = blockIdx.x * 256 + threadIdx.x;
    if (e < N_EDGES) {
        int s = ei[2 * e];
        int d = ei[2 * e + 1];
        int pos = atomicAdd(&ptr[d], 1);              // after: ptr[d] == end
        srcl[pos] = s;
    }
}

// -------- aggregation: y[i] = dinv[i]*(dinv[i]*x[i] + sum_s dinv[s]*x[s]) --------
// wave-per-node, float2/lane, shfl-broadcast edge data, 4x batched loads for MLP.

__global__ __launch_bounds__(256) void k_aggregate(
        const float* __restrict__ x, const float* __restrict__ dinv,
        const int* __restrict__ ptr, const int* __restrict__ counts,
        const int* __restrict__ srcl, float* __restrict__ y) {
    int wv = threadIdx.x >> 6;
    int lane = threadIdx.x & 63;
    int i = blockIdx.x * 4 + wv;
    if (i >= N_NODES) return;
    float di = dinv[i];
    int end = ptr[i];
    int start = end - counts[i];
    const float2* __restrict__ x2 = (const float2*)x;
    float2 xv = x2[i * 64 + lane];
    float sx = di * xv.x, sy = di * xv.y;            // self-loop term
    for (int e0 = start; e0 < end; e0 += 64) {
        int ne = end - e0; if (ne > 64) ne = 64;
        int s = 0; float w = 0.f;
        if (lane < ne) {
            s = srcl[e0 + lane];
            w = dinv[s];
        }
        int t = 0;
        for (; t + 4 <= ne; t += 4) {
            int s0 = __shfl(s, t),     s1 = __shfl(s, t + 1);
            int s2 = __shfl(s, t + 2), s3 = __shfl(s, t + 3);
            float w0 = __shfl(w, t),     w1 = __shfl(w, t + 1);
            float w2 = __shfl(w, t + 2), w3 = __shfl(w, t + 3);
            float2 a = x2[s0 * 64 + lane];
            float2 b = x2[s1 * 64 + lane];
            float2 c = x2[s2 * 64 + lane];
            float2 d = x2[s3 * 64 + lane];
            sx += w0 * a.x + w1 * b.x + w2 * c.x + w3 * d.x;
            sy += w0 * a.y + w1 * b.y + w2 * c.y + w3 * d.y;
        }
        for (; t < ne; ++t) {
            int st = __shfl(s, t); float wt = __shfl(w, t);
            float2 a = x2[st * 64 + lane];
            sx += wt * a.x; sy += wt * a.y;
        }
    }
    float2 o; o.x = di * sx; o.y = di * sy;
    ((float2*)y)[i * 64 + lane] = o;
}

// ---------------- GEMM: out = relu(y @ W^T + b) via split-bf16 MFMA ----------------
// D = A*B: A = y rows (m), B-frag rows = W rows (n), both [16]x[K] along K.
// mfma_f32_16x16x32_bf16 layouts (verified m89/m120):
//   A: lane&15 = m, k = (lane>>4)*8 + j       B: lane&15 = n, same k mapping
//   C/D: col = lane&15, row = (lane>>4)*4 + reg
// Split: v = hi + lo (bf16 each); acc += hi*hi + hi*lo + lo*hi  (error ~2^-16 rel)

#define BM 64
#define BN 64
#define BK 64
#define LDK 72   // padded K-stride (bf16 elems): 144B rows -> 16B aligned, 2-way banks (free)

__device__ __forceinline__ unsigned short f2bf(float f) {
    unsigned u = __float_as_uint(f);
    return (unsigned short)((u + 0x7fffu + ((u >> 16) & 1u)) >> 16);
}
__device__ __forceinline__ float bf2f(unsigned short h) {
    return __uint_as_float(((unsigned)h) << 16);
}

__global__ __launch_bounds__(256) void k_gemm(
        const float* __restrict__ y, const float* __restrict__ W,
        const float* __restrict__ bias, float* __restrict__ out) {
    __shared__ unsigned short Ah[BM * LDK], Al[BM * LDK];
    __shared__ unsigned short Bh[BN * LDK], Bl[BN * LDK];
    int tid = threadIdx.x;
    int lane = tid & 63;
    int wv = tid >> 6;
    int jb = blockIdx.x * BN;        // n-block fastest-varying -> y-tile L2 reuse
    int i0 = blockIdx.y * BM;
    int n0 = wv * 16;
    int rl = lane & 15;              // m (A) / n (B) row within 16-tile
    int quad = lane >> 4;

    f32x4 acc[4] = {{0.f,0.f,0.f,0.f},{0.f,0.f,0.f,0.f},{0.f,0.f,0.f,0.f},{0.f,0.f,0.f,0.f}};

    for (int kc = 0; kc < IN_DIM; kc += BK) {
        __syncthreads();
        #pragma unroll
        for (int it = 0; it < 4; ++it) {
            int g = it * 256 + tid;          // 0..1023
            int r = g >> 4;                  // 0..63
            int c4 = g & 15;                 // float4 index along k
            int row = i0 + r; if (row >= N_NODES) row = N_NODES - 1;
            float4 v = *(const float4*)&y[row * IN_DIM + kc + c4 * 4];
            float4 wv4 = *(const float4*)&W[(jb + r) * IN_DIM + kc + c4 * 4];
            int a = r * LDK + c4 * 4;
            {
                unsigned short h0 = f2bf(v.x), h1 = f2bf(v.y), h2 = f2bf(v.z), h3 = f2bf(v.w);
                *(ushort4*)&Ah[a] = make_ushort4(h0, h1, h2, h3);
                *(ushort4*)&Al[a] = make_ushort4(
                    f2bf(v.x - bf2f(h0)), f2bf(v.y - bf2f(h1)),
                    f2bf(v.z - bf2f(h2)), f2bf(v.w - bf2f(h3)));
            }
            {
                unsigned short h0 = f2bf(wv4.x), h1 = f2bf(wv4.y), h2 = f2bf(wv4.z), h3 = f2bf(wv4.w);
                *(ushort4*)&Bh[a] = make_ushort4(h0, h1, h2, h3);
                *(ushort4*)&Bl[a] = make_ushort4(
                    f2bf(wv4.x - bf2f(h0)), f2bf(wv4.y - bf2f(h1)),
                    f2bf(wv4.z - bf2f(h2)), f2bf(wv4.w - bf2f(h3)));
            }
        }
        __syncthreads();
        #pragma unroll
        for (int ks = 0; ks < 2; ++ks) {
            int koff = ks * 32 + quad * 8;
            bf16x8 bh = *(bf16x8*)&Bh[(n0 + rl) * LDK + koff];
            bf16x8 bl = *(bf16x8*)&Bl[(n0 + rl) * LDK + koff];
            #pragma unroll
            for (int mt = 0; mt < 4; ++mt) {
                bf16x8 ah = *(bf16x8*)&Ah[(mt * 16 + rl) * LDK + koff];
                bf16x8 al = *(bf16x8*)&Al[(mt * 16 + rl) * LDK + koff];
                acc[mt] = __builtin_amdgcn_mfma_f32_16x16x32_bf16(ah, bh, acc[mt], 0, 0, 0);
                acc[mt] = __builtin_amdgcn_mfma_f32_16x16x32_bf16(ah, bl, acc[mt], 0, 0, 0);
                acc[mt] = __builtin_amdgcn_mfma_f32_16x16x32_bf16(al, bh, acc[mt], 0, 0, 0);
            }
        }
    }

    float bv = bias[jb + n0 + rl];
    #pragma unroll
    for (int mt = 0; mt < 4; ++mt) {
        #pragma unroll
        for (int r = 0; r < 4; ++r) {
            int row = i0 + mt * 16 + quad * 4 + r;
            if (row < N_NODES) {
                float v = acc[mt][r] + bv;
                out[row * OUT_DIM + jb + n0 + rl] = fmaxf(v, 0.f);
            }
        }
    }
}

// ---------------- launch ----------------

extern "C" void kernel_launch(void* const* d_in, const int* in_sizes, int n_in,
                              void* d_out, int out_size, void* d_ws, size_t ws_size,
                              hipStream_t stream) {
    const float* x  = (const float*)d_in[0];
    const int*   ei = (const int*)d_in[1];
    const float* W  = (const float*)d_in[2];
    const float* b  = (const float*)d_in[3];
    float* out = (float*)d_out;

    char* ws = (char*)d_ws;
    int*   counts = (int*)(ws + 0);          //  50000 ints
    int*   ptr    = (int*)(ws + 200704);     //  50000 ints
    int*   bsum   = (int*)(ws + 401408);     //  64 ints
    float* dinv   = (float*)(ws + 401664);   //  50000 floats
    int*   srcl   = (int*)(ws + 602368);     //  800000 ints
    float* y      = (float*)(ws + 3802368);  //  6400000 floats

    hipMemsetAsync(counts, 0, N_NODES * sizeof(int), stream);

    k_hist<<<(N_EDGES + 255) / 256, 256, 0, stream>>>(ei, counts);
    k_scan1<<<SCAN_BLOCKS, 1024, 0, stream>>>(counts, ptr, bsum);
    k_scan2<<<1, 64, 0, stream>>>(bsum);
    k_finalize<<<(N_NODES + 255) / 256, 256, 0, stream>>>(ptr, counts, bsum, dinv);
    k_scatter<<<(N_EDGES + 255) / 256, 256, 0, stream>>>(ei, ptr, srcl);
    k_aggregate<<<(N_NODES + 3) / 4, 256, 0, stream>>>(x, dinv, ptr, counts, srcl, y);

    dim3 g(OUT_DIM / BN, (N_NODES + BM - 1) / BM);   // n fastest -> y-tile reuse in L2
    k_gemm<<<g, 256, 0, stream>>>(y, W, b, out);
}